// Round 1
// baseline (546.810 us; speedup 1.0000x reference)
//
#include <hip/hip_runtime.h>
#include <math.h>

// Problem constants
#define Bb   4
#define Ss   1024
#define Ee   1024
#define Nn   16
#define Hh   64
#define Ff   4096
#define Rr   2048
#define NHh  1024   // N*H
#define BSs  4096   // B*S
#define QKVLD 3072  // fused qkv row stride

typedef short v8s __attribute__((ext_vector_type(8)));
typedef float v4f __attribute__((ext_vector_type(4)));
typedef unsigned short v4us __attribute__((ext_vector_type(4)));
typedef unsigned int u32;
typedef unsigned short us;

static __device__ inline us f2bf(float f) {
    u32 u = __builtin_bit_cast(u32, f);
    u += 0x7fffu + ((u >> 16) & 1u);   // RNE
    return (us)(u >> 16);
}
static __device__ inline float bf2f(us h) {
    u32 u = ((u32)h) << 16;
    return __builtin_bit_cast(float, u);
}
static __device__ inline void g2lds16(const void* g, void* l) {
    __builtin_amdgcn_global_load_lds(
        (const __attribute__((address_space(1))) u32*)g,
        (__attribute__((address_space(3))) u32*)l, 16, 0, 0);
}

// ---------------------------------------------------------------------------
// Transpose + cvt core: in [K][N] fp32 -> out [N][K] bf16, 32x32 tile.
// ---------------------------------------------------------------------------
static __device__ __forceinline__ void tr_core(
    float (*t)[33],
    const float* __restrict__ in, us* __restrict__ out,
    int K, int N, int i0, int j0)
{
    const int r  = threadIdx.x >> 3;
    const int c4 = (threadIdx.x & 7) * 4;
    const float4 v = *reinterpret_cast<const float4*>(in + (size_t)(i0 + r) * N + j0 + c4);
    t[r][c4 + 0] = v.x; t[r][c4 + 1] = v.y; t[r][c4 + 2] = v.z; t[r][c4 + 3] = v.w;
    __syncthreads();
    ushort4 o;
    o.x = f2bf(t[c4 + 0][r]); o.y = f2bf(t[c4 + 1][r]);
    o.z = f2bf(t[c4 + 2][r]); o.w = f2bf(t[c4 + 3][r]);
    *reinterpret_cast<ushort4*>(out + (size_t)(j0 + r) * K + i0 + c4) = o;
}

// ---------------------------------------------------------------------------
// One merged prep kernel: x/rpe cvt (blocks [0,12288)), 5 square weight
// transposes ([12288,17408)), Wi/Wout transposes ([17408,25600)).
// ---------------------------------------------------------------------------
__global__ __launch_bounds__(256) void prep_all(
    const float* __restrict__ x, us* __restrict__ x16,
    const float* __restrict__ rpe, us* __restrict__ rpe16,
    const float* __restrict__ Wq, const float* __restrict__ Wk,
    const float* __restrict__ Wv, const float* __restrict__ Wr,
    const float* __restrict__ Wo,
    us* __restrict__ Wqkv_t, us* __restrict__ Wr_t, us* __restrict__ Wo_t,
    const float* __restrict__ Wi, us* __restrict__ Wi_t,
    const float* __restrict__ Wout, us* __restrict__ Wout_t)
{
    __shared__ float t[32][33];
    const int bid = blockIdx.x;
    if (bid < 12288) {
        const float* in; us* out; size_t base;
        if (bid < 4096) { in = x; out = x16; base = (size_t)bid; }
        else { in = rpe; out = rpe16; base = (size_t)(bid - 4096); }
        const size_t i = (base * 256 + threadIdx.x) * 4;
        const float4 v = *reinterpret_cast<const float4*>(in + i);
        ushort4 o;
        o.x = f2bf(v.x); o.y = f2bf(v.y); o.z = f2bf(v.z); o.w = f2bf(v.w);
        *reinterpret_cast<ushort4*>(out + i) = o;
    } else if (bid < 17408) {
        const int local = bid - 12288;
        const int z = local >> 10;
        const int rem = local & 1023;
        const int i0 = (rem >> 5) * 32;
        const int j0 = (rem & 31) * 32;
        const float* in; us* out;
        switch (z) {
            case 0: in = Wq; out = Wqkv_t; break;
            case 1: in = Wk; out = Wqkv_t + 1024 * 1024; break;
            case 2: in = Wv; out = Wqkv_t + 2048 * 1024; break;
            case 3: in = Wr; out = Wr_t; break;
            default: in = Wo; out = Wo_t; break;
        }
        tr_core(t, in, out, 1024, 1024, i0, j0);
    } else {
        const int local = bid - 17408;
        if (local < 4096) {
            const int xb = local & 127, yb = local >> 7;
            tr_core(t, Wi, Wi_t, 1024, 4096, yb * 32, xb * 32);
        } else {
            const int l2 = local - 4096;
            const int xb = l2 & 127, yb = l2 >> 7;
            tr_core(t, Wout, Wout_t, 4096, 1024, xb * 32, yb * 32);
        }
    }
}

// ---------------------------------------------------------------------------
// Per-(b,n) transpose of V: v16 (stride ld) [B,S,*] -> vT16 [B,N,H,S] bf16.
// ---------------------------------------------------------------------------
__global__ __launch_bounds__(256) void transpose_v(
    const us* __restrict__ v16, us* __restrict__ vT16, int ld)
{
    __shared__ us T[64][72];
    const int s0 = blockIdx.x * 64;
    const int bn = blockIdx.y;          // b*16 + n
    const int b  = bn >> 4, n = bn & 15;
    const int t  = threadIdx.x;
    {
        const int r = t >> 2, c = (t & 3) * 16;
        const uint4* src = (const uint4*)(v16 + (size_t)(b * Ss + s0 + r) * ld + n * 64 + c);
        *(uint4*)&T[r][c]     = src[0];
        *(uint4*)&T[r][c + 8] = src[1];
    }
    __syncthreads();
    {
        const int h = t >> 2, c2 = (t & 3) * 16;
        us tmp[16];
        #pragma unroll
        for (int u = 0; u < 16; ++u) tmp[u] = T[c2 + u][h];
        us* dst = vT16 + (size_t)(bn * 64 + h) * Ss + s0 + c2;
        *(uint4*)dst       = *(uint4*)tmp;
        *(uint4*)(dst + 8) = *(uint4*)(tmp + 8);
    }
}

// ---------------------------------------------------------------------------
// bf16 MFMA GEMM body: C = A[M,K] @ B^T (B as [N][K]).
// Tile: (MT*32) x 128, BK=64, 4 waves 2x2; XOR-swizzled LDS (see R6/R7).
// ---------------------------------------------------------------------------
template<int MT, int OUT_BF16, int BIAS, int RELU>
static __device__ __forceinline__ void gemm_body(
    us* __restrict__ Asm, us* __restrict__ Bsm,
    const us* __restrict__ A, const us* __restrict__ B,
    const float* __restrict__ bias, void* __restrict__ Cv,
    int K, int ldC, int row0, int col0)
{
    const int tid  = threadIdx.x;
    const int lane = tid & 63;
    const int wave = tid >> 6;
    const int wr   = wave >> 1, wc = wave & 1;
    const int lrow = lane & 15;
    const int lq   = lane >> 4;
    const int h3   = lrow & 7;

    v4f acc[MT][4];
    #pragma unroll
    for (int mt = 0; mt < MT; ++mt)
        #pragma unroll
        for (int nt = 0; nt < 4; ++nt)
            acc[mt][nt] = (v4f){0.f, 0.f, 0.f, 0.f};

    for (int k0 = 0; k0 < K; k0 += 64) {
        #pragma unroll
        for (int u = 0; u < MT; ++u) {
            const int slot = u * 256 + tid;
            const int sr = slot >> 3;
            const int sc = ((slot & 7) ^ (sr & 7)) * 8;
            g2lds16(A + (size_t)(row0 + sr) * K + k0 + sc, &Asm[slot * 8]);
        }
        #pragma unroll
        for (int u = 0; u < 4; ++u) {
            const int slot = u * 256 + tid;
            const int sr = slot >> 3;
            const int sc = ((slot & 7) ^ (sr & 7)) * 8;
            g2lds16(B + (size_t)(col0 + sr) * K + k0 + sc, &Bsm[slot * 8]);
        }
        __syncthreads();

        #pragma unroll
        for (int t = 0; t < 2; ++t) {
            const int cc = ((lq + 4 * t) ^ h3) * 8;
            v8s af[MT], bf[4];
            #pragma unroll
            for (int mt = 0; mt < MT; ++mt)
                af[mt] = *reinterpret_cast<const v8s*>(
                    &Asm[(wr * (MT * 16) + mt * 16 + lrow) * 64 + cc]);
            #pragma unroll
            for (int nt = 0; nt < 4; ++nt)
                bf[nt] = *reinterpret_cast<const v8s*>(
                    &Bsm[(wc * 64 + nt * 16 + lrow) * 64 + cc]);
            #pragma unroll
            for (int mt = 0; mt < MT; ++mt)
                #pragma unroll
                for (int nt = 0; nt < 4; ++nt)
                    acc[mt][nt] = __builtin_amdgcn_mfma_f32_16x16x32_bf16(
                        af[mt], bf[nt], acc[mt][nt], 0, 0, 0);
        }
        __syncthreads();
    }

    #pragma unroll
    for (int nt = 0; nt < 4; ++nt) {
        const int col = col0 + wc * 64 + nt * 16 + lrow;
        const float bv = BIAS ? bias[col] : 0.f;
        #pragma unroll
        for (int mt = 0; mt < MT; ++mt) {
            #pragma unroll
            for (int v = 0; v < 4; ++v) {
                const int row = row0 + wr * (MT * 16) + mt * 16 + lq * 4 + v;
                float val = acc[mt][nt][v] + bv;
                if (RELU) val = fmaxf(val, 0.f);
                if (OUT_BF16)
                    ((us*)Cv)[(size_t)row * ldC + col] = f2bf(val);
                else
                    ((float*)Cv)[(size_t)row * ldC + col] = val;
            }
        }
    }
}

template<int MT, int OUT_BF16, int BIAS, int RELU>
__global__ __launch_bounds__(256) void gemm_tile(
    const us* __restrict__ A, const us* __restrict__ B,
    const float* __restrict__ bias, void* __restrict__ Cv,
    int K, int ldC)
{
    __shared__ us Asm[MT * 32 * 64];
    __shared__ us Bsm[128 * 64];
    gemm_body<MT, OUT_BF16, BIAS, RELU>(Asm, Bsm, A, B, bias, Cv, K, ldC,
                                        blockIdx.y * (MT * 32), blockIdx.x * 128);
}

// Fused QKV (768 blocks) + R (512 blocks) projection in one 1280-block launch.
__global__ __launch_bounds__(256) void gemm_qkv_r(
    const us* __restrict__ x16, const us* __restrict__ Wqkv,
    us* __restrict__ qkv, const us* __restrict__ rpe16,
    const us* __restrict__ Wr, us* __restrict__ rout)
{
    __shared__ us Asm[128 * 64];
    __shared__ us Bsm[128 * 64];
    const int bid = blockIdx.x;
    if (bid < 768) {
        gemm_body<4,1,0,0>(Asm, Bsm, x16, Wqkv, nullptr, qkv, Ee, QKVLD,
                           (bid / 24) * 128, (bid % 24) * 128);
    } else {
        const int b2 = bid - 768;
        gemm_body<4,1,0,0>(Asm, Bsm, rpe16, Wr, nullptr, rout, Ee, NHh,
                           (b2 / 8) * 128, (b2 % 8) * 128);
    }
}

// ---------------------------------------------------------------------------
// MFMA flash attention with rel-shift ring buffer.
// R9: barrier-free. K/R/V MFMA B-fragments are 16B-contiguous in global
// (qkv rows over H, r16 rows over H, vT16 rows over S) -> loaded directly
// per-lane from global (L2-resident per XCD via bn-mod-8 swizzle; the 4
// waves of a block read identical addresses -> L1 absorbs the redundancy).
// A-fragments (qc/qp) built per-lane from global in the prologue.
// Remaining LDS (ring + Pt) is wave-private -> NO __syncthreads at all.
// LDS 53760 -> 26112 B: all 4 blocks/CU resident (entire grid resident),
// killing the 3+1 residency tail that held occupancy at 25.9%.
// Softmax scale*log2e folded into qc/qp so the exp is a raw exp2f.
// ---------------------------------------------------------------------------
#define PTP 68     // Pt pitch
#define RP 68      // ring cm row pitch (64 rows + 4 pad; even*4 for b64 align)

static __device__ __forceinline__ v8s bias_scale(
    v8s q, const float* __restrict__ bias, float scale)
{
    v8s o;
    #pragma unroll
    for (int u = 0; u < 8; ++u)
        o[u] = (short)f2bf((bf2f((us)q[u]) + bias[u]) * scale);
    return o;
}

__global__ __launch_bounds__(256, 4) void attn_mfma(
    const us* __restrict__ qkv, const us* __restrict__ vT16,
    const us* __restrict__ r16,
    const float* __restrict__ cb, const float* __restrict__ pb,
    us* __restrict__ attn)
{
    __shared__ __align__(16) char smem[26112];
    us* ring = (us*)smem;               // cm: 128 cols x 68-row pitch = 17408 B
    us* Pt   = (us*)(smem + 17408);     // 64 x 68 bf16 = 8704 B

    const int bn = blockIdx.x;          // b*16 + n  (XCD = bn & 7)
    const int b  = bn >> 4;
    const int n  = bn & 15;
    const int i0 = blockIdx.y * 64;
    const int tid  = threadIdx.x;
    const int lane = tid & 63;
    const int w    = tid >> 6;
    const int quad = lane >> 4;
    const int l15  = lane & 15;
    const int w16  = w * 16;

    const float SCALE = 0.125f * 1.44269504088896f;   // 1/sqrt(H) * log2(e)

    // ---- Prologue: A-fragments qc/qp built per-lane direct from global ----
    v8s aqc0, aqc1, aqp0, aqp1;
    {
        const us* qrow = qkv + (size_t)(b * Ss + i0 + w16 + l15) * QKVLD + n * 64;
        const v8s q0 = *(const v8s*)(qrow + quad * 8);
        const v8s q1 = *(const v8s*)(qrow + 32 + quad * 8);
        const float* cbp = cb + n * 64 + quad * 8;
        const float* pbp = pb + n * 64 + quad * 8;
        aqc0 = bias_scale(q0, cbp,      SCALE);
        aqc1 = bias_scale(q1, cbp + 32, SCALE);
        aqp0 = bias_scale(q0, pbp,      SCALE);
        aqp1 = bias_scale(q1, pbp + 32, SCALE);
    }

    const int c0 = Ss - i0;   // l at j-i diag base

    // ---- Bootstrap: pos chunk l in [c0-64, c0) -> ring cols j in [irow-i0-64, irow-i0) ----
    {
        const us* rrow = r16 + (size_t)(b * Rr + (c0 - 64)) * NHh + n * 64 + quad * 8;
        const v4f z = (v4f){0.f, 0.f, 0.f, 0.f};
        #pragma unroll
        for (int t = 0; t < 4; ++t) {
            const us* rp = rrow + (size_t)(t * 16 + l15) * NHh;
            v8s br0 = *(const v8s*)rp;
            v8s br1 = *(const v8s*)(rp + 32);
            v4f pp = __builtin_amdgcn_mfma_f32_16x16x32_bf16(aqp0, br0, z, 0, 0, 0);
            pp = __builtin_amdgcn_mfma_f32_16x16x32_bf16(aqp1, br1, pp, 0, 0, 0);
            const int colbase = t * 16 + l15 - 64;   // j = colbase + irow
            #pragma unroll
            for (int v = 0; v < 4; ++v) {
                const int irow = w16 + quad * 4 + v;
                ring[((colbase + irow) & 127) * RP + irow] = f2bf(pp[v]);
            }
        }
    }

    v4f Oa[4];
    #pragma unroll
    for (int t = 0; t < 4; ++t) Oa[t] = (v4f){0.f, 0.f, 0.f, 0.f};
    float la[4] = {0.f, 0.f, 0.f, 0.f};

    // Per-lane base pointers; advanced per key-tile.
    const us* kp = qkv  + (size_t)(b * Ss + l15) * QKVLD + NHh + n * 64 + quad * 8;
    const us* rp = r16  + (size_t)(b * Rr + c0 + l15) * NHh + n * 64 + quad * 8;
    const us* vp = vT16 + (size_t)(bn * 64 + l15) * Ss + quad * 8;

    // ---- Main flash loop over key tiles (barrier-free) ----
    for (int j0 = 0; j0 < Ss; j0 += 64) {
        const v4f z = (v4f){0.f, 0.f, 0.f, 0.f};

        // Content scores (K direct from global)
        v4f sc[4];
        #pragma unroll
        for (int t = 0; t < 4; ++t) {
            const us* kt = kp + (size_t)(t * 16) * QKVLD;
            v8s bk0 = *(const v8s*)kt;
            v8s bk1 = *(const v8s*)(kt + 32);
            sc[t] = __builtin_amdgcn_mfma_f32_16x16x32_bf16(aqc0, bk0, z, 0, 0, 0);
            sc[t] = __builtin_amdgcn_mfma_f32_16x16x32_bf16(aqc1, bk1, sc[t], 0, 0, 0);
        }

        // Pos chunk (R direct from global) -> ring (skewed cm: col = j & 127)
        #pragma unroll
        for (int t = 0; t < 4; ++t) {
            const us* rt = rp + (size_t)(t * 16) * NHh;
            v8s br0 = *(const v8s*)rt;
            v8s br1 = *(const v8s*)(rt + 32);
            v4f pp = __builtin_amdgcn_mfma_f32_16x16x32_bf16(aqp0, br0, z, 0, 0, 0);
            pp = __builtin_amdgcn_mfma_f32_16x16x32_bf16(aqp1, br1, pp, 0, 0, 0);
            const int colbase = j0 + t * 16 + l15;
            #pragma unroll
            for (int v = 0; v < 4; ++v) {
                const int irow = w16 + quad * 4 + v;
                ring[((colbase + irow) & 127) * RP + irow] = f2bf(pp[v]);
            }
        }

        // Scores -> exp2 -> Pt; pos gathered via one b64 per t (4 rows packed)
        #pragma unroll
        for (int t = 0; t < 4; ++t) {
            const v4us pr = *(const v4us*)&ring[((j0 + t * 16 + l15) & 127) * RP + w16 + quad * 4];
            #pragma unroll
            for (int v = 0; v < 4; ++v) {
                const int irow = w16 + quad * 4 + v;
                const float p = exp2f(sc[t][v] + bf2f(pr[v]));
                la[v] += p;
                Pt[irow * PTP + t * 16 + l15] = f2bf(p);
            }
        }

        // PV (V direct from global)
        v8s pa0 = *(v8s*)&Pt[(w16 + l15) * PTP + quad * 8];
        v8s pa1 = *(v8s*)&Pt[(w16 + l15) * PTP + 32 + quad * 8];
        __builtin_amdgcn_s_setprio(1);
        #pragma unroll
        for (int ht = 0; ht < 4; ++ht) {
            const us* vt = vp + (size_t)(ht * 16) * Ss;
            v8s bv0 = *(const v8s*)vt;
            v8s bv1 = *(const v8s*)(vt + 32);
            Oa[ht] = __builtin_amdgcn_mfma_f32_16x16x32_bf16(pa0, bv0, Oa[ht], 0, 0, 0);
            Oa[ht] = __builtin_amdgcn_mfma_f32_16x16x32_bf16(pa1, bv1, Oa[ht], 0, 0, 0);
        }
        __builtin_amdgcn_s_setprio(0);

        kp += (size_t)64 * QKVLD;
        rp += (size_t)64 * NHh;
        vp += 64;
    }

    // ---- Epilogue: reduce row sums across quad, normalize, store ----
    #pragma unroll
    for (int v = 0; v < 4; ++v) {
        la[v] += __shfl_xor(la[v], 1);
        la[v] += __shfl_xor(la[v], 2);
        la[v] += __shfl_xor(la[v], 4);
        la[v] += __shfl_xor(la[v], 8);
        la[v] = 1.f / la[v];
    }
    #pragma unroll
    for (int ht = 0; ht < 4; ++ht) {
        #pragma unroll
        for (int v = 0; v < 4; ++v) {
            const int irow = w16 + quad * 4 + v;
            attn[(size_t)(b * Ss + i0 + irow) * NHh + n * 64 + ht * 16 + l15] =
                f2bf(Oa[ht][v] * la[v]);
        }
    }
}

// ---------------------------------------------------------------------------
// Fused residual-add + LayerNorm over E=1024; optional bf16 copy of output.
// ---------------------------------------------------------------------------
template<int W16>
__global__ __launch_bounds__(256) void add_ln_kernel(
    const float* __restrict__ a, const float* __restrict__ res,
    const float* __restrict__ g, const float* __restrict__ bet,
    float* __restrict__ out, us* __restrict__ out16)
{
    const int row = blockIdx.x;
    const int tid = threadIdx.x;
    const float* ar = a   + (size_t)row * Ee;
    const float* rr = res + (size_t)row * Ee;

    float vals[4];
    float lsum = 0.f, lsq = 0.f;
    #pragma unroll
    for (int it = 0; it < 4; ++it) {
        const int idx = tid + it * 256;
        const float vv = ar[idx] + rr[idx];
        vals[it] = vv;
        lsum += vv;
        lsq  = fmaf(vv, vv, lsq);
    }
    #pragma unroll
    for (int off = 32; off > 0; off >>= 1) {
        lsum += __shfl_down(lsum, off);
        lsq  += __shfl_down(lsq,  off);
    }
    __shared__ float w1[4], w2[4];
    if ((tid & 63) == 0) { w1[tid >> 6] = lsum; w2[tid >> 6] = lsq; }
    __syncthreads();
    const float sum  = w1[0] + w1[1] + w1[2] + w1[3];
    const float sq   = w2[0] + w2[1] + w2[2] + w2[3];
    const float mean = sum * (1.f / 1024.f);
    const float var  = sq * (1.f / 1024.f) - mean * mean;
    const float rstd = rsqrtf(var + 1e-12f);
    #pragma unroll
    for (int it = 0; it < 4; ++it) {
        const int idx = tid + it * 256;
        const float o = (vals[it] - mean) * rstd * g[idx] + bet[idx];
        out[(size_t)row * Ee + idx] = o;
        if (W16) out16[(size_t)row * Ee + idx] = f2bf(o);
    }
}

// ---------------------------------------------------------------------------
// Orchestration. Workspace layout (1 MB units), 90 MB total:
//   [ 0, 8)  x16      -> attn16 (ph3)  -> inner16 head (ph6)
//   [ 8,24)  rpe16    -> vT16 [8,16) (ph2.5), ao fp32 [16,24) (ph4)
//   [24,30)  Wqkv_t   [30,32) Wr_t   [32,34) Wo_t      (inner16 covers 0..32)
//   [34,42)  Wi_t     [42,50) Wout_t
//   [50,74)  qkv16    -> h16 [50,58) + hb fp32 [58,74) (ph5)
//   [74,90)  r16      -> out2 fp32 (ph7)
// ---------------------------------------------------------------------------
#define MB (1u << 20)

extern "C" void kernel_launch(void* const* d_in, const int* in_sizes, int n_in,
                              void* d_out, int out_size, void* d_ws, size_t ws_size,
                              hipStream_t stream)
{
    (void)in_sizes; (void)n_in; (void)out_size; (void)ws_size;

    const float* x    = (const float*)d_in[0];
    const float* cbf  = (const float*)d_in[1];
    const float* pbf  = (const float*)d_in[2];
    const float* rpe  = (const float*)d_in[3];
    const float* Wq   = (const float*)d_in[4];
    const float* Wk   = (const float*)d_in[5];
    const float* Wv   = (const float*)d_in[6];
    const float* Wr   = (const float*)d_in[7];
    const float* Wo   = (const float*)d_in[8];
    const float* ln1g = (const float*)d_in[9];
    const float* ln1b = (const float*)d_in[10];
    const float* Wi   = (const float*)d_in[11];
    const float* bi   = (const float*)d_in[12];
    const float* Wout = (const float*)d_in[13];
    const float* bout = (const float*)d_in[14];
    const float* ln2g = (const float*)d_in[15];
    const float* ln2b = (const float*)d_in[16];

    float* out = (float*)d_out;
    char*  ws  = (char*)d_ws;

    us* x16    = (us*)(ws + 0 * MB);
    us* rpe16  = (us*)(ws + 8 * MB);
    us* Wqkv_t = (us*)(ws + 24 * MB);           // [3072][1024]
    us* Wr_t   = (us*)(ws + 30 * MB);
    us* Wo_t   = (us*)(ws + 32 * MB);
    us* Wi_t   = (us*)(ws + 34 * MB);
    us* Wout_t = (us*)(ws + 42 * MB);
    us* qkv16  = (us*)(ws + 50 * MB);           // [BS][3072]
    us* r16    = (us*)(ws + 74 * MB);
    us* vT16   = (us*)(ws + 8 * MB);            // reuse rpe16 (after qkv_r gemm)
    us* attn16 = (us*)(ws + 0 * MB);            // reuse x16
    float* ao  = (float*)(ws + 16 * MB);        // [16,24)
    us* h16    = (us*)(ws + 50 * MB);           // reuse qkv16
    float* hb  = (float*)(ws + 58 * MB);        // reuse qkv16 tail
    us* inner16= (us*)(ws + 0 * MB);            // 0..32 MB
    float* out2= (float*)(ws + 74 * MB);        // reuse r16

    const dim3 blk(256);

    // Phase 1: all converts + transposes, one dispatch
    prep_all<<<dim3(25600), blk, 0, stream>>>(
        x, x16, rpe, rpe16, Wq, Wk, Wv, Wr, Wo,
        Wqkv_t, Wr_t, Wo_t, Wi, Wi_t, Wout, Wout_t);

    // Phase 2: fused QKV + R projection (one 1280-block dispatch)
    gemm_qkv_r<<<dim3(1280), blk, 0, stream>>>(x16, Wqkv_t, qkv16, rpe16, Wr_t, r16);

    // Phase 2.5: V transpose (v cols of qkv) -> [B,N,H,S]
    transpose_v<<<dim3(16, 64), blk, 0, stream>>>(qkv16 + 2048, vT16, QKVLD);

    // Phase 3: MFMA flash attention; grid (bn, i) for XCD-local K/R/V reuse
    attn_mfma<<<dim3(64, 16), blk, 0, stream>>>(qkv16, vT16, r16, cbf, pbf, attn16);

    // Phase 4: output projection (fp32 out), 64-row tiles -> 512 blocks (2/CU)
    gemm_tile<2,0,0,0><<<dim3(8, 64), blk, 0, stream>>>(attn16, Wo_t, nullptr, ao, NHh, Ee);

    // Phase 5: h = LN1(ao + x), fp32 + bf16
    add_ln_kernel<1><<<dim3(BSs), blk, 0, stream>>>(ao, x, ln1g, ln1b, hb, h16);

    // Phase 6: FFN1 (bias+relu, bf16 out), 128-row tiles, 1024 blocks
    gemm_tile<4,1,1,1><<<dim3(32, 32), blk, 0, stream>>>(h16, Wi_t, bi, inner16, Ee, Ff);

    // Phase 7: FFN2 (bias, fp32 out), 64-row tiles -> 512 blocks (2+/CU)
    gemm_tile<2,0,1,0><<<dim3(8, 64), blk, 0, stream>>>(inner16, Wout_t, bout, out2, Ff, Ee);

    // Phase 8: out = LN2(out2 + h)
    add_ln_kernel<0><<<dim3(BSs), blk, 0, stream>>>(out2, hb, ln2g, ln2b, out, nullptr);
}

// Round 2
// 431.107 us; speedup vs baseline: 1.2684x; 1.2684x over previous
//
#include <hip/hip_runtime.h>
#include <math.h>

// Problem constants
#define Bb   4
#define Ss   1024
#define Ee   1024
#define Nn   16
#define Hh   64
#define Ff   4096
#define Rr   2048
#define NHh  1024   // N*H
#define BSs  4096   // B*S
#define QKVLD 3072  // fused qkv row stride

typedef short v8s __attribute__((ext_vector_type(8)));
typedef float v4f __attribute__((ext_vector_type(4)));
typedef unsigned short v4us __attribute__((ext_vector_type(4)));
typedef unsigned int u32;
typedef unsigned short us;

static __device__ inline us f2bf(float f) {
    u32 u = __builtin_bit_cast(u32, f);
    u += 0x7fffu + ((u >> 16) & 1u);   // RNE
    return (us)(u >> 16);
}
static __device__ inline float bf2f(us h) {
    u32 u = ((u32)h) << 16;
    return __builtin_bit_cast(float, u);
}
static __device__ inline void g2lds16(const void* g, void* l) {
    __builtin_amdgcn_global_load_lds(
        (const __attribute__((address_space(1))) u32*)g,
        (__attribute__((address_space(3))) u32*)l, 16, 0, 0);
}

// ---------------------------------------------------------------------------
// Transpose + cvt core: in [K][N] fp32 -> out [N][K] bf16, 32x32 tile.
// ---------------------------------------------------------------------------
static __device__ __forceinline__ void tr_core(
    float (*t)[33],
    const float* __restrict__ in, us* __restrict__ out,
    int K, int N, int i0, int j0)
{
    const int r  = threadIdx.x >> 3;
    const int c4 = (threadIdx.x & 7) * 4;
    const float4 v = *reinterpret_cast<const float4*>(in + (size_t)(i0 + r) * N + j0 + c4);
    t[r][c4 + 0] = v.x; t[r][c4 + 1] = v.y; t[r][c4 + 2] = v.z; t[r][c4 + 3] = v.w;
    __syncthreads();
    ushort4 o;
    o.x = f2bf(t[c4 + 0][r]); o.y = f2bf(t[c4 + 1][r]);
    o.z = f2bf(t[c4 + 2][r]); o.w = f2bf(t[c4 + 3][r]);
    *reinterpret_cast<ushort4*>(out + (size_t)(j0 + r) * K + i0 + c4) = o;
}

// ---------------------------------------------------------------------------
// One merged prep kernel: x/rpe cvt (blocks [0,12288)), 5 square weight
// transposes ([12288,17408)), Wi/Wout transposes ([17408,25600)).
// ---------------------------------------------------------------------------
__global__ __launch_bounds__(256) void prep_all(
    const float* __restrict__ x, us* __restrict__ x16,
    const float* __restrict__ rpe, us* __restrict__ rpe16,
    const float* __restrict__ Wq, const float* __restrict__ Wk,
    const float* __restrict__ Wv, const float* __restrict__ Wr,
    const float* __restrict__ Wo,
    us* __restrict__ Wqkv_t, us* __restrict__ Wr_t, us* __restrict__ Wo_t,
    const float* __restrict__ Wi, us* __restrict__ Wi_t,
    const float* __restrict__ Wout, us* __restrict__ Wout_t)
{
    __shared__ float t[32][33];
    const int bid = blockIdx.x;
    if (bid < 12288) {
        const float* in; us* out; size_t base;
        if (bid < 4096) { in = x; out = x16; base = (size_t)bid; }
        else { in = rpe; out = rpe16; base = (size_t)(bid - 4096); }
        const size_t i = (base * 256 + threadIdx.x) * 4;
        const float4 v = *reinterpret_cast<const float4*>(in + i);
        ushort4 o;
        o.x = f2bf(v.x); o.y = f2bf(v.y); o.z = f2bf(v.z); o.w = f2bf(v.w);
        *reinterpret_cast<ushort4*>(out + i) = o;
    } else if (bid < 17408) {
        const int local = bid - 12288;
        const int z = local >> 10;
        const int rem = local & 1023;
        const int i0 = (rem >> 5) * 32;
        const int j0 = (rem & 31) * 32;
        const float* in; us* out;
        switch (z) {
            case 0: in = Wq; out = Wqkv_t; break;
            case 1: in = Wk; out = Wqkv_t + 1024 * 1024; break;
            case 2: in = Wv; out = Wqkv_t + 2048 * 1024; break;
            case 3: in = Wr; out = Wr_t; break;
            default: in = Wo; out = Wo_t; break;
        }
        tr_core(t, in, out, 1024, 1024, i0, j0);
    } else {
        const int local = bid - 17408;
        if (local < 4096) {
            const int xb = local & 127, yb = local >> 7;
            tr_core(t, Wi, Wi_t, 1024, 4096, yb * 32, xb * 32);
        } else {
            const int l2 = local - 4096;
            const int xb = l2 & 127, yb = l2 >> 7;
            tr_core(t, Wout, Wout_t, 4096, 1024, xb * 32, yb * 32);
        }
    }
}

// ---------------------------------------------------------------------------
// Per-(b,n) transpose of V: v16 (stride ld) [B,S,*] -> vT16 [B,N,H,S] bf16.
// ---------------------------------------------------------------------------
__global__ __launch_bounds__(256) void transpose_v(
    const us* __restrict__ v16, us* __restrict__ vT16, int ld)
{
    __shared__ us T[64][72];
    const int s0 = blockIdx.x * 64;
    const int bn = blockIdx.y;          // b*16 + n
    const int b  = bn >> 4, n = bn & 15;
    const int t  = threadIdx.x;
    {
        const int r = t >> 2, c = (t & 3) * 16;
        const uint4* src = (const uint4*)(v16 + (size_t)(b * Ss + s0 + r) * ld + n * 64 + c);
        *(uint4*)&T[r][c]     = src[0];
        *(uint4*)&T[r][c + 8] = src[1];
    }
    __syncthreads();
    {
        const int h = t >> 2, c2 = (t & 3) * 16;
        us tmp[16];
        #pragma unroll
        for (int u = 0; u < 16; ++u) tmp[u] = T[c2 + u][h];
        us* dst = vT16 + (size_t)(bn * 64 + h) * Ss + s0 + c2;
        *(uint4*)dst       = *(uint4*)tmp;
        *(uint4*)(dst + 8) = *(uint4*)(tmp + 8);
    }
}

// ---------------------------------------------------------------------------
// bf16 MFMA GEMM body: C = A[M,K] @ B^T (B as [N][K]).
// Tile: (MT*32) x 128, BK=64, 4 waves 2x2; XOR-swizzled LDS (see R6/R7).
// ---------------------------------------------------------------------------
template<int MT, int OUT_BF16, int BIAS, int RELU>
static __device__ __forceinline__ void gemm_body(
    us* __restrict__ Asm, us* __restrict__ Bsm,
    const us* __restrict__ A, const us* __restrict__ B,
    const float* __restrict__ bias, void* __restrict__ Cv,
    int K, int ldC, int row0, int col0)
{
    const int tid  = threadIdx.x;
    const int lane = tid & 63;
    const int wave = tid >> 6;
    const int wr   = wave >> 1, wc = wave & 1;
    const int lrow = lane & 15;
    const int lq   = lane >> 4;
    const int h3   = lrow & 7;

    v4f acc[MT][4];
    #pragma unroll
    for (int mt = 0; mt < MT; ++mt)
        #pragma unroll
        for (int nt = 0; nt < 4; ++nt)
            acc[mt][nt] = (v4f){0.f, 0.f, 0.f, 0.f};

    for (int k0 = 0; k0 < K; k0 += 64) {
        #pragma unroll
        for (int u = 0; u < MT; ++u) {
            const int slot = u * 256 + tid;
            const int sr = slot >> 3;
            const int sc = ((slot & 7) ^ (sr & 7)) * 8;
            g2lds16(A + (size_t)(row0 + sr) * K + k0 + sc, &Asm[slot * 8]);
        }
        #pragma unroll
        for (int u = 0; u < 4; ++u) {
            const int slot = u * 256 + tid;
            const int sr = slot >> 3;
            const int sc = ((slot & 7) ^ (sr & 7)) * 8;
            g2lds16(B + (size_t)(col0 + sr) * K + k0 + sc, &Bsm[slot * 8]);
        }
        __syncthreads();

        #pragma unroll
        for (int t = 0; t < 2; ++t) {
            const int cc = ((lq + 4 * t) ^ h3) * 8;
            v8s af[MT], bf[4];
            #pragma unroll
            for (int mt = 0; mt < MT; ++mt)
                af[mt] = *reinterpret_cast<const v8s*>(
                    &Asm[(wr * (MT * 16) + mt * 16 + lrow) * 64 + cc]);
            #pragma unroll
            for (int nt = 0; nt < 4; ++nt)
                bf[nt] = *reinterpret_cast<const v8s*>(
                    &Bsm[(wc * 64 + nt * 16 + lrow) * 64 + cc]);
            #pragma unroll
            for (int mt = 0; mt < MT; ++mt)
                #pragma unroll
                for (int nt = 0; nt < 4; ++nt)
                    acc[mt][nt] = __builtin_amdgcn_mfma_f32_16x16x32_bf16(
                        af[mt], bf[nt], acc[mt][nt], 0, 0, 0);
        }
        __syncthreads();
    }

    #pragma unroll
    for (int nt = 0; nt < 4; ++nt) {
        const int col = col0 + wc * 64 + nt * 16 + lrow;
        const float bv = BIAS ? bias[col] : 0.f;
        #pragma unroll
        for (int mt = 0; mt < MT; ++mt) {
            #pragma unroll
            for (int v = 0; v < 4; ++v) {
                const int row = row0 + wr * (MT * 16) + mt * 16 + lq * 4 + v;
                float val = acc[mt][nt][v] + bv;
                if (RELU) val = fmaxf(val, 0.f);
                if (OUT_BF16)
                    ((us*)Cv)[(size_t)row * ldC + col] = f2bf(val);
                else
                    ((float*)Cv)[(size_t)row * ldC + col] = val;
            }
        }
    }
}

template<int MT, int OUT_BF16, int BIAS, int RELU>
__global__ __launch_bounds__(256) void gemm_tile(
    const us* __restrict__ A, const us* __restrict__ B,
    const float* __restrict__ bias, void* __restrict__ Cv,
    int K, int ldC)
{
    __shared__ us Asm[MT * 32 * 64];
    __shared__ us Bsm[128 * 64];
    gemm_body<MT, OUT_BF16, BIAS, RELU>(Asm, Bsm, A, B, bias, Cv, K, ldC,
                                        blockIdx.y * (MT * 32), blockIdx.x * 128);
}

// Fused QKV (768 blocks) + R (512 blocks) projection in one 1280-block launch.
__global__ __launch_bounds__(256) void gemm_qkv_r(
    const us* __restrict__ x16, const us* __restrict__ Wqkv,
    us* __restrict__ qkv, const us* __restrict__ rpe16,
    const us* __restrict__ Wr, us* __restrict__ rout)
{
    __shared__ us Asm[128 * 64];
    __shared__ us Bsm[128 * 64];
    const int bid = blockIdx.x;
    if (bid < 768) {
        gemm_body<4,1,0,0>(Asm, Bsm, x16, Wqkv, nullptr, qkv, Ee, QKVLD,
                           (bid / 24) * 128, (bid % 24) * 128);
    } else {
        const int b2 = bid - 768;
        gemm_body<4,1,0,0>(Asm, Bsm, rpe16, Wr, nullptr, rout, Ee, NHh,
                           (b2 / 8) * 128, (b2 % 8) * 128);
    }
}

// ---------------------------------------------------------------------------
// MFMA flash attention with rel-shift ring buffer.
// R10: R8 staged structure (bulk coalesced stage -> barrier -> LDS compute),
// with LDS shrunk 53760 -> 40960 B so all 4 blocks/CU are resident (R8 had
// 3/CU + a 1/CU tail = measured 25.9% occupancy). Changes vs R8:
//  - Kt/Rt/VtT: pitch 64 + 16B-granule XOR swizzle (granule ^= row&7): 8192 B
//    each, b128 reads/writes at the conflict floor.
//  - ring: pitch 64, row-XOR swizzle (irow ^= (col&7)<<3): 16384 B.
//  - Pt overlays Kt (both wave-private by row); one extra barrier after the
//    pos-MFMA phase guarantees all waves' Kt reads precede Pt writes.
//  - q A-fragments built per-lane direct from global (prologue-only; no LDS).
//  - scale folded with log2e -> raw exp2f; s_setprio(1) around PV MFMAs.
// ---------------------------------------------------------------------------
__global__ __launch_bounds__(256, 4) void attn_mfma(
    const us* __restrict__ qkv, const us* __restrict__ vT16,
    const us* __restrict__ r16,
    const float* __restrict__ cb, const float* __restrict__ pb,
    us* __restrict__ attn)
{
    __shared__ __align__(16) us smem[20480];    // 40960 B
    us* Kt   = smem;            // 64 x 64 swz (8192 B); overlaid by Pt
    us* Rt   = smem + 4096;     // 64 x 64 swz
    us* VtT  = smem + 8192;     // 64 x 64 swz
    us* ring = smem + 12288;    // 128 cols x 64 rows, row-XOR swz (16384 B)
    us* Pt   = Kt;              // overlay

    const int bn = blockIdx.x;         // b*16 + n  (XCD = bn & 7)
    const int b  = bn >> 4;
    const int n  = bn & 15;
    const int i0 = blockIdx.y * 64;
    const int tid  = threadIdx.x;
    const int lane = tid & 63;
    const int w    = tid >> 6;
    const int quad = lane >> 4;
    const int l15  = lane & 15;
    const int l7   = l15 & 7;
    const int w16  = w * 16;

    const float SCALE = 0.125f * 1.44269504088896f;   // 1/sqrt(H) * log2(e)

    // ---- Prologue: A-fragments qc/qp built per-lane direct from global ----
    v8s aqc0, aqc1, aqp0, aqp1;
    {
        const us* qrow = qkv + (size_t)(b * Ss + i0 + w16 + l15) * QKVLD + n * 64;
        const v8s q0 = *(const v8s*)(qrow + quad * 8);
        const v8s q1 = *(const v8s*)(qrow + 32 + quad * 8);
        const float* cbp = cb + n * 64 + quad * 8;
        const float* pbp = pb + n * 64 + quad * 8;
        #pragma unroll
        for (int u = 0; u < 8; ++u) {
            const float f0 = bf2f((us)q0[u]);
            const float f1 = bf2f((us)q1[u]);
            aqc0[u] = (short)f2bf((f0 + cbp[u])      * SCALE);
            aqc1[u] = (short)f2bf((f1 + cbp[u + 32]) * SCALE);
            aqp0[u] = (short)f2bf((f0 + pbp[u])      * SCALE);
            aqp1[u] = (short)f2bf((f1 + pbp[u + 32]) * SCALE);
        }
    }

    const int c0 = Ss - i0;   // l at j-i diag base

    // Staging geometry (shared by bootstrap + main loop)
    const int sgr = tid >> 2;            // row 0..63
    const int scg = (tid & 3) * 2;       // first 16B granule (0,2,4,6)
    const int srx = sgr & 7;
    us* const kd0 = &Kt [sgr * 64 + ((scg ^ srx) << 3)];
    us* const kd1 = &Kt [sgr * 64 + (((scg + 1) ^ srx) << 3)];
    us* const rd0 = &Rt [sgr * 64 + ((scg ^ srx) << 3)];
    us* const rd1 = &Rt [sgr * 64 + (((scg + 1) ^ srx) << 3)];
    us* const vd0 = &VtT[sgr * 64 + ((scg ^ srx) << 3)];
    us* const vd1 = &VtT[sgr * 64 + (((scg + 1) ^ srx) << 3)];

    // ---- Bootstrap: pos chunk l in [c0-64, c0) -> ring cols j in [irow-i0-64, irow-i0) ----
    {
        const uint4* sr = (const uint4*)(r16 + (size_t)(b * Rr + (c0 - 64) + sgr) * NHh + n * 64 + scg * 8);
        uint4 r0v = sr[0], r1v = sr[1];
        *(uint4*)rd0 = r0v;
        *(uint4*)rd1 = r1v;
        __syncthreads();
        const v4f z = (v4f){0.f, 0.f, 0.f, 0.f};
        #pragma unroll
        for (int t = 0; t < 4; ++t) {
            const int row = t * 16 + l15;
            v8s br0 = *(const v8s*)&Rt[row * 64 + ((quad ^ l7) << 3)];
            v8s br1 = *(const v8s*)&Rt[row * 64 + (((quad + 4) ^ l7) << 3)];
            v4f pp = __builtin_amdgcn_mfma_f32_16x16x32_bf16(aqp0, br0, z, 0, 0, 0);
            pp = __builtin_amdgcn_mfma_f32_16x16x32_bf16(aqp1, br1, pp, 0, 0, 0);
            const int colbase = t * 16 + l15 - 64;   // j = colbase + irow
            #pragma unroll
            for (int v = 0; v < 4; ++v) {
                const int irow = w16 + quad * 4 + v;
                const int col = (colbase + irow) & 127;
                ring[col * 64 + (irow ^ ((col & 7) << 3))] = f2bf(pp[v]);
            }
        }
    }

    v4f Oa[4];
    #pragma unroll
    for (int t = 0; t < 4; ++t) Oa[t] = (v4f){0.f, 0.f, 0.f, 0.f};
    float la[4] = {0.f, 0.f, 0.f, 0.f};

    // ---- Main flash loop over key tiles ----
    for (int j0 = 0; j0 < Ss; j0 += 64) {
        __syncthreads();   // B1: prev iter Pt/VtT/bootstrap Rt reads done
        {
            const uint4* sk = (const uint4*)(qkv + (size_t)(b * Ss + j0 + sgr) * QKVLD + NHh + n * 64 + scg * 8);
            const uint4* sr = (const uint4*)(r16 + (size_t)(b * Rr + (j0 + c0) + sgr) * NHh + n * 64 + scg * 8);
            const uint4* sv = (const uint4*)(vT16 + (size_t)(bn * 64 + sgr) * Ss + j0 + scg * 8);
            uint4 k0v = sk[0], k1v = sk[1];
            uint4 r0v = sr[0], r1v = sr[1];
            uint4 v0v = sv[0], v1v = sv[1];
            *(uint4*)kd0 = k0v;  *(uint4*)kd1 = k1v;
            *(uint4*)rd0 = r0v;  *(uint4*)rd1 = r1v;
            *(uint4*)vd0 = v0v;  *(uint4*)vd1 = v1v;
        }
        __syncthreads();   // B2: stage visible

        const v4f z = (v4f){0.f, 0.f, 0.f, 0.f};
        // Content scores
        v4f sc[4];
        #pragma unroll
        for (int t = 0; t < 4; ++t) {
            const int row = t * 16 + l15;
            v8s bk0 = *(const v8s*)&Kt[row * 64 + ((quad ^ l7) << 3)];
            v8s bk1 = *(const v8s*)&Kt[row * 64 + (((quad + 4) ^ l7) << 3)];
            sc[t] = __builtin_amdgcn_mfma_f32_16x16x32_bf16(aqc0, bk0, z, 0, 0, 0);
            sc[t] = __builtin_amdgcn_mfma_f32_16x16x32_bf16(aqc1, bk1, sc[t], 0, 0, 0);
        }
        // Pos chunk -> ring (skewed cm: col = j & 127, row-XOR swizzle)
        #pragma unroll
        for (int t = 0; t < 4; ++t) {
            const int row = t * 16 + l15;
            v8s br0 = *(const v8s*)&Rt[row * 64 + ((quad ^ l7) << 3)];
            v8s br1 = *(const v8s*)&Rt[row * 64 + (((quad + 4) ^ l7) << 3)];
            v4f pp = __builtin_amdgcn_mfma_f32_16x16x32_bf16(aqp0, br0, z, 0, 0, 0);
            pp = __builtin_amdgcn_mfma_f32_16x16x32_bf16(aqp1, br1, pp, 0, 0, 0);
            const int colbase = j0 + t * 16 + l15;
            #pragma unroll
            for (int v = 0; v < 4; ++v) {
                const int irow = w16 + quad * 4 + v;
                const int col = (colbase + irow) & 127;
                ring[col * 64 + (irow ^ ((col & 7) << 3))] = f2bf(pp[v]);
            }
        }

        __syncthreads();   // B3: all waves' Kt reads done -> Pt may overwrite

        // Scores -> exp2 -> Pt (=Kt); pos gathered via one b64 per t
        #pragma unroll
        for (int t = 0; t < 4; ++t) {
            const int col = (j0 + t * 16 + l15) & 127;
            const int rbase = (w16 + quad * 4) ^ ((col & 7) << 3);
            const v4us pr = *(const v4us*)&ring[col * 64 + rbase];
            const int j = t * 16 + l15;
            const int gsw = j >> 3;            // 2t + (l15>>3)
            #pragma unroll
            for (int v = 0; v < 4; ++v) {
                const int irow = w16 + quad * 4 + v;
                const float p = exp2f(sc[t][v] + bf2f(pr[v]));
                la[v] += p;
                Pt[irow * 64 + (((gsw ^ (irow & 7)) << 3) | (j & 7))] = f2bf(p);
            }
        }

        // PV
        v8s pa0 = *(v8s*)&Pt[(w16 + l15) * 64 + ((quad ^ l7) << 3)];
        v8s pa1 = *(v8s*)&Pt[(w16 + l15) * 64 + (((quad + 4) ^ l7) << 3)];
        __builtin_amdgcn_s_setprio(1);
        #pragma unroll
        for (int ht = 0; ht < 4; ++ht) {
            const int row = ht * 16 + l15;
            v8s bv0 = *(const v8s*)&VtT[row * 64 + ((quad ^ l7) << 3)];
            v8s bv1 = *(const v8s*)&VtT[row * 64 + (((quad + 4) ^ l7) << 3)];
            Oa[ht] = __builtin_amdgcn_mfma_f32_16x16x32_bf16(pa0, bv0, Oa[ht], 0, 0, 0);
            Oa[ht] = __builtin_amdgcn_mfma_f32_16x16x32_bf16(pa1, bv1, Oa[ht], 0, 0, 0);
        }
        __builtin_amdgcn_s_setprio(0);
    }

    // ---- Epilogue: reduce row sums across quad, normalize, store ----
    #pragma unroll
    for (int v = 0; v < 4; ++v) {
        la[v] += __shfl_xor(la[v], 1);
        la[v] += __shfl_xor(la[v], 2);
        la[v] += __shfl_xor(la[v], 4);
        la[v] += __shfl_xor(la[v], 8);
        la[v] = 1.f / la[v];
    }
    #pragma unroll
    for (int ht = 0; ht < 4; ++ht) {
        #pragma unroll
        for (int v = 0; v < 4; ++v) {
            const int irow = w16 + quad * 4 + v;
            attn[(size_t)(b * Ss + i0 + irow) * NHh + n * 64 + ht * 16 + l15] =
                f2bf(Oa[ht][v] * la[v]);
        }
    }
}

// ---------------------------------------------------------------------------
// Fused residual-add + LayerNorm over E=1024; optional bf16 copy of output.
// ---------------------------------------------------------------------------
template<int W16>
__global__ __launch_bounds__(256) void add_ln_kernel(
    const float* __restrict__ a, const float* __restrict__ res,
    const float* __restrict__ g, const float* __restrict__ bet,
    float* __restrict__ out, us* __restrict__ out16)
{
    const int row = blockIdx.x;
    const int tid = threadIdx.x;
    const float* ar = a   + (size_t)row * Ee;
    const float* rr = res + (size_t)row * Ee;

    float vals[4];
    float lsum = 0.f, lsq = 0.f;
    #pragma unroll
    for (int it = 0; it < 4; ++it) {
        const int idx = tid + it * 256;
        const float vv = ar[idx] + rr[idx];
        vals[it] = vv;
        lsum += vv;
        lsq  = fmaf(vv, vv, lsq);
    }
    #pragma unroll
    for (int off = 32; off > 0; off >>= 1) {
        lsum += __shfl_down(lsum, off);
        lsq  += __shfl_down(lsq,  off);
    }
    __shared__ float w1[4], w2[4];
    if ((tid & 63) == 0) { w1[tid >> 6] = lsum; w2[tid >> 6] = lsq; }
    __syncthreads();
    const float sum  = w1[0] + w1[1] + w1[2] + w1[3];
    const float sq   = w2[0] + w2[1] + w2[2] + w2[3];
    const float mean = sum * (1.f / 1024.f);
    const float var  = sq * (1.f / 1024.f) - mean * mean;
    const float rstd = rsqrtf(var + 1e-12f);
    #pragma unroll
    for (int it = 0; it < 4; ++it) {
        const int idx = tid + it * 256;
        const float o = (vals[it] - mean) * rstd * g[idx] + bet[idx];
        out[(size_t)row * Ee + idx] = o;
        if (W16) out16[(size_t)row * Ee + idx] = f2bf(o);
    }
}

// ---------------------------------------------------------------------------
// Orchestration. Workspace layout (1 MB units), 90 MB total:
//   [ 0, 8)  x16      -> attn16 (ph3)  -> inner16 head (ph6)
//   [ 8,24)  rpe16    -> vT16 [8,16) (ph2.5), ao fp32 [16,24) (ph4)
//   [24,30)  Wqkv_t   [30,32) Wr_t   [32,34) Wo_t      (inner16 covers 0..32)
//   [34,42)  Wi_t     [42,50) Wout_t
//   [50,74)  qkv16    -> h16 [50,58) + hb fp32 [58,74) (ph5)
//   [74,90)  r16      -> out2 fp32 (ph7)
// ---------------------------------------------------------------------------
#define MB (1u << 20)

extern "C" void kernel_launch(void* const* d_in, const int* in_sizes, int n_in,
                              void* d_out, int out_size, void* d_ws, size_t ws_size,
                              hipStream_t stream)
{
    (void)in_sizes; (void)n_in; (void)out_size; (void)ws_size;

    const float* x    = (const float*)d_in[0];
    const float* cbf  = (const float*)d_in[1];
    const float* pbf  = (const float*)d_in[2];
    const float* rpe  = (const float*)d_in[3];
    const float* Wq   = (const float*)d_in[4];
    const float* Wk   = (const float*)d_in[5];
    const float* Wv   = (const float*)d_in[6];
    const float* Wr   = (const float*)d_in[7];
    const float* Wo   = (const float*)d_in[8];
    const float* ln1g = (const float*)d_in[9];
    const float* ln1b = (const float*)d_in[10];
    const float* Wi   = (const float*)d_in[11];
    const float* bi   = (const float*)d_in[12];
    const float* Wout = (const float*)d_in[13];
    const float* bout = (const float*)d_in[14];
    const float* ln2g = (const float*)d_in[15];
    const float* ln2b = (const float*)d_in[16];

    float* out = (float*)d_out;
    char*  ws  = (char*)d_ws;

    us* x16    = (us*)(ws + 0 * MB);
    us* rpe16  = (us*)(ws + 8 * MB);
    us* Wqkv_t = (us*)(ws + 24 * MB);           // [3072][1024]
    us* Wr_t   = (us*)(ws + 30 * MB);
    us* Wo_t   = (us*)(ws + 32 * MB);
    us* Wi_t   = (us*)(ws + 34 * MB);
    us* Wout_t = (us*)(ws + 42 * MB);
    us* qkv16  = (us*)(ws + 50 * MB);           // [BS][3072]
    us* r16    = (us*)(ws + 74 * MB);
    us* vT16   = (us*)(ws + 8 * MB);            // reuse rpe16 (after qkv_r gemm)
    us* attn16 = (us*)(ws + 0 * MB);            // reuse x16
    float* ao  = (float*)(ws + 16 * MB);        // [16,24)
    us* h16    = (us*)(ws + 50 * MB);           // reuse qkv16
    float* hb  = (float*)(ws + 58 * MB);        // reuse qkv16 tail
    us* inner16= (us*)(ws + 0 * MB);            // 0..32 MB
    float* out2= (float*)(ws + 74 * MB);        // reuse r16

    const dim3 blk(256);

    // Phase 1: all converts + transposes, one dispatch
    prep_all<<<dim3(25600), blk, 0, stream>>>(
        x, x16, rpe, rpe16, Wq, Wk, Wv, Wr, Wo,
        Wqkv_t, Wr_t, Wo_t, Wi, Wi_t, Wout, Wout_t);

    // Phase 2: fused QKV + R projection (one 1280-block dispatch)
    gemm_qkv_r<<<dim3(1280), blk, 0, stream>>>(x16, Wqkv_t, qkv16, rpe16, Wr_t, r16);

    // Phase 2.5: V transpose (v cols of qkv) -> [B,N,H,S]
    transpose_v<<<dim3(16, 64), blk, 0, stream>>>(qkv16 + 2048, vT16, QKVLD);

    // Phase 3: MFMA flash attention; grid (bn, i) for XCD-local K/R/V reuse
    attn_mfma<<<dim3(64, 16), blk, 0, stream>>>(qkv16, vT16, r16, cbf, pbf, attn16);

    // Phase 4: output projection (fp32 out), 64-row tiles -> 512 blocks (2/CU)
    gemm_tile<2,0,0,0><<<dim3(8, 64), blk, 0, stream>>>(attn16, Wo_t, nullptr, ao, NHh, Ee);

    // Phase 5: h = LN1(ao + x), fp32 + bf16
    add_ln_kernel<1><<<dim3(BSs), blk, 0, stream>>>(ao, x, ln1g, ln1b, hb, h16);

    // Phase 6: FFN1 (bias+relu, bf16 out), 128-row tiles, 1024 blocks
    gemm_tile<4,1,1,1><<<dim3(32, 32), blk, 0, stream>>>(h16, Wi_t, bi, inner16, Ee, Ff);

    // Phase 7: FFN2 (bias, fp32 out), 64-row tiles -> 512 blocks (2+/CU)
    gemm_tile<2,0,1,0><<<dim3(8, 64), blk, 0, stream>>>(inner16, Wout_t, bout, out2, Ff, Ee);

    // Phase 8: out = LN2(out2 + h)
    add_ln_kernel<0><<<dim3(BSs), blk, 0, stream>>>(out2, hb, ln2g, ln2b, out, nullptr);
}